// Round 2
// baseline (917.254 us; speedup 1.0000x reference)
//
#include <hip/hip_runtime.h>
#include <hip/hip_bf16.h>
#include <math.h>

#define D 128
#define DPAD 136   // +8 bf16 pad: row stride 272B = 68 words -> rows shift 4 banks
#define BM 64      // edge/node rows per block

typedef __attribute__((ext_vector_type(8))) short bf16x8;
typedef __attribute__((ext_vector_type(4))) float f32x4;

__device__ __forceinline__ unsigned short f2bf(float f) {
    unsigned int u = __float_as_uint(f);
    unsigned int r = u + 0x7fffu + ((u >> 16) & 1u);
    return (unsigned short)(r >> 16);
}

__device__ __forceinline__ float silu(float x) {
    return x / (1.f + __expf(-x));
}

// ---------------- weight convert: 4 x [128x128] f32 -> bf16 -------------
__global__ void convert_weights(const float* __restrict__ a, const float* __restrict__ b,
                                const float* __restrict__ c, const float* __restrict__ d,
                                unsigned short* __restrict__ o) {
    int i = blockIdx.x * 256 + threadIdx.x;          // 0..65535
    const float* p = (i < 16384) ? a : (i < 32768) ? b : (i < 49152) ? c : d;
    o[i] = f2bf(p[i & 16383]);
}

// ---------------- edge-degree counts ------------------------------------
__global__ void count_edges(const int* __restrict__ tgt_idx, float* __restrict__ counts, int n_edge) {
    int i = blockIdx.x * 256 + threadIdx.x;
    if (i < n_edge) atomicAdd(&counts[tgt_idx[i]], 1.0f);
}

// ---------------- shared GEMM core pieces -------------------------------
// Block: 256 thr = 4 waves; tile BM x 128 out, K = 128.
// Wave w computes rows [w*16, w*16+16). Per wave: 8 col-tiles x 4 k-steps MFMA.

__device__ __forceinline__ void stage_B(const unsigned short* __restrict__ Wb,
                                        unsigned short (*Bs)[DPAD], int tid) {
    const int4* src = (const int4*)Wb;               // 8 shorts per chunk; 16 chunks/row
#pragma unroll
    for (int i = 0; i < 8; ++i) {                    // 2048 chunks = 128 rows x 16 chunks
        int linear = tid + i * 256;
        int row = linear >> 4, c8 = (linear & 15) * 8;
        *(int4*)&Bs[row][c8] = src[linear];
    }
}

// ---------------- projection GEMM: O = A @ W^T (fp32 in, fp32 out) ------
__global__ __launch_bounds__(256) void proj_kernel(const float* __restrict__ A,
                                                   const unsigned short* __restrict__ Wb,
                                                   float* __restrict__ O, int M) {
    __shared__ unsigned short As[BM][DPAD];
    __shared__ unsigned short Bs[D][DPAD];
    int tid = threadIdx.x;
    int m0 = blockIdx.x * BM;
    stage_B(Wb, Bs, tid);
#pragma unroll
    for (int i = 0; i < 8; ++i) {                    // 2048 float4 chunks
        int linear = tid + i * 256;
        int row = linear >> 5, c4 = (linear & 31) * 4;
        int gr = m0 + row; if (gr >= M) gr = M - 1;
        float4 v = *(const float4*)&A[(size_t)gr * D + c4];
        unsigned int lo = (unsigned int)f2bf(v.x) | ((unsigned int)f2bf(v.y) << 16);
        unsigned int hi = (unsigned int)f2bf(v.z) | ((unsigned int)f2bf(v.w) << 16);
        *(uint2*)&As[row][c4] = make_uint2(lo, hi);
    }
    __syncthreads();

    int wid = tid >> 6, lane = tid & 63, q = lane >> 4, ln = lane & 15;
    f32x4 acc[8];
#pragma unroll
    for (int nt = 0; nt < 8; ++nt) acc[nt] = (f32x4){0.f, 0.f, 0.f, 0.f};
    int arow = wid * 16 + ln;
#pragma unroll
    for (int k0 = 0; k0 < 128; k0 += 32) {
        bf16x8 a = *(const bf16x8*)&As[arow][k0 + q * 8];
#pragma unroll
        for (int nt = 0; nt < 8; ++nt) {
            bf16x8 b = *(const bf16x8*)&Bs[nt * 16 + ln][k0 + q * 8];
            acc[nt] = __builtin_amdgcn_mfma_f32_16x16x32_bf16(a, b, acc[nt], 0, 0, 0);
        }
    }
#pragma unroll
    for (int r = 0; r < 4; ++r) {
        int grow = m0 + wid * 16 + q * 4 + r;
        if (grow < M) {
#pragma unroll
            for (int nt = 0; nt < 8; ++nt)
                O[(size_t)grow * D + nt * 16 + ln] = acc[nt][r];
        }
    }
}

// ---------------- fused edge kernel -------------------------------------
// acc = edge_feat @ We2e^T ; h = acc + Sp[src] + Tp[tgt]; silu; LN ->
// edge_out = edge_feat + a ; atomic scatter a into sums[tgt]
__global__ __launch_bounds__(256) void edge_kernel(const float* __restrict__ edge_feat,
                                                   const unsigned short* __restrict__ We2e_b,
                                                   const float* __restrict__ Sp,
                                                   const float* __restrict__ Tp,
                                                   const int* __restrict__ src_idx,
                                                   const int* __restrict__ tgt_idx,
                                                   const float* __restrict__ gamma1,
                                                   const float* __restrict__ beta1,
                                                   float* __restrict__ edge_out,
                                                   float* __restrict__ sums,
                                                   int n_edge) {
    __shared__ unsigned short As[BM][DPAD];
    __shared__ unsigned short Bs[D][DPAD];
    int tid = threadIdx.x;
    int e0 = blockIdx.x * BM;
    stage_B(We2e_b, Bs, tid);
#pragma unroll
    for (int i = 0; i < 8; ++i) {
        int linear = tid + i * 256;
        int row = linear >> 5, c4 = (linear & 31) * 4;
        int gr = e0 + row; if (gr >= n_edge) gr = n_edge - 1;
        float4 v = *(const float4*)&edge_feat[(size_t)gr * D + c4];
        unsigned int lo = (unsigned int)f2bf(v.x) | ((unsigned int)f2bf(v.y) << 16);
        unsigned int hi = (unsigned int)f2bf(v.z) | ((unsigned int)f2bf(v.w) << 16);
        *(uint2*)&As[row][c4] = make_uint2(lo, hi);
    }
    __syncthreads();

    int wid = tid >> 6, lane = tid & 63, q = lane >> 4, ln = lane & 15;
    f32x4 acc[8];
#pragma unroll
    for (int nt = 0; nt < 8; ++nt) acc[nt] = (f32x4){0.f, 0.f, 0.f, 0.f};
    int arow = wid * 16 + ln;
#pragma unroll
    for (int k0 = 0; k0 < 128; k0 += 32) {
        bf16x8 a = *(const bf16x8*)&As[arow][k0 + q * 8];
#pragma unroll
        for (int nt = 0; nt < 8; ++nt) {
            bf16x8 b = *(const bf16x8*)&Bs[nt * 16 + ln][k0 + q * 8];
            acc[nt] = __builtin_amdgcn_mfma_f32_16x16x32_bf16(a, b, acc[nt], 0, 0, 0);
        }
    }

    float g[8], bt[8];
#pragma unroll
    for (int nt = 0; nt < 8; ++nt) { g[nt] = gamma1[nt * 16 + ln]; bt[nt] = beta1[nt * 16 + ln]; }

#pragma unroll
    for (int r = 0; r < 4; ++r) {
        int e = e0 + wid * 16 + q * 4 + r;          // uniform across the 16-lane quad
        if (e >= n_edge) continue;
        int s = src_idx[e], t = tgt_idx[e];
        float h[8], sum = 0.f, sumsq = 0.f;
#pragma unroll
        for (int nt = 0; nt < 8; ++nt) {
            int c = nt * 16 + ln;
            float v = acc[nt][r] + Sp[(size_t)s * D + c] + Tp[(size_t)t * D + c];
            v = silu(v);
            h[nt] = v; sum += v; sumsq += v * v;
        }
#pragma unroll
        for (int m = 1; m < 16; m <<= 1) {           // row lives on 16 lanes of this quad
            sum += __shfl_xor(sum, m);
            sumsq += __shfl_xor(sumsq, m);
        }
        float mean = sum * (1.f / 128.f);
        float var = sumsq * (1.f / 128.f) - mean * mean;
        float rs = rsqrtf(var + 1e-5f);
#pragma unroll
        for (int nt = 0; nt < 8; ++nt) {
            int c = nt * 16 + ln;
            float a = (h[nt] - mean) * rs * g[nt] + bt[nt];
            edge_out[(size_t)e * D + c] = edge_feat[(size_t)e * D + c] + a;
            atomicAdd(&sums[(size_t)t * D + c], a);
        }
    }
}

// ---------------- fused node kernel -------------------------------------
// agg = sums/max(counts,1); acc = agg @ We2t^T; h = acc + Ttp; silu; LN;
// tgt_out = tgt_feat + a
__global__ __launch_bounds__(256) void node_kernel(const float* __restrict__ sums,
                                                   const float* __restrict__ counts,
                                                   const unsigned short* __restrict__ We2t_b,
                                                   const float* __restrict__ Ttp,
                                                   const float* __restrict__ tgt_feat,
                                                   const float* __restrict__ gamma2,
                                                   const float* __restrict__ beta2,
                                                   float* __restrict__ tgt_out,
                                                   int n_tgt) {
    __shared__ unsigned short As[BM][DPAD];
    __shared__ unsigned short Bs[D][DPAD];
    int tid = threadIdx.x;
    int m0 = blockIdx.x * BM;
    stage_B(We2t_b, Bs, tid);
#pragma unroll
    for (int i = 0; i < 8; ++i) {
        int linear = tid + i * 256;
        int row = linear >> 5, c4 = (linear & 31) * 4;
        int gr = m0 + row; if (gr >= n_tgt) gr = n_tgt - 1;
        float rcp = 1.f / fmaxf(counts[gr], 1.f);
        float4 v = *(const float4*)&sums[(size_t)gr * D + c4];
        unsigned int lo = (unsigned int)f2bf(v.x * rcp) | ((unsigned int)f2bf(v.y * rcp) << 16);
        unsigned int hi = (unsigned int)f2bf(v.z * rcp) | ((unsigned int)f2bf(v.w * rcp) << 16);
        *(uint2*)&As[row][c4] = make_uint2(lo, hi);
    }
    __syncthreads();

    int wid = tid >> 6, lane = tid & 63, q = lane >> 4, ln = lane & 15;
    f32x4 acc[8];
#pragma unroll
    for (int nt = 0; nt < 8; ++nt) acc[nt] = (f32x4){0.f, 0.f, 0.f, 0.f};
    int arow = wid * 16 + ln;
#pragma unroll
    for (int k0 = 0; k0 < 128; k0 += 32) {
        bf16x8 a = *(const bf16x8*)&As[arow][k0 + q * 8];
#pragma unroll
        for (int nt = 0; nt < 8; ++nt) {
            bf16x8 b = *(const bf16x8*)&Bs[nt * 16 + ln][k0 + q * 8];
            acc[nt] = __builtin_amdgcn_mfma_f32_16x16x32_bf16(a, b, acc[nt], 0, 0, 0);
        }
    }

    float g[8], bt[8];
#pragma unroll
    for (int nt = 0; nt < 8; ++nt) { g[nt] = gamma2[nt * 16 + ln]; bt[nt] = beta2[nt * 16 + ln]; }

#pragma unroll
    for (int r = 0; r < 4; ++r) {
        int row = m0 + wid * 16 + q * 4 + r;
        if (row >= n_tgt) continue;
        float h[8], sum = 0.f, sumsq = 0.f;
#pragma unroll
        for (int nt = 0; nt < 8; ++nt) {
            int c = nt * 16 + ln;
            float v = acc[nt][r] + Ttp[(size_t)row * D + c];
            v = silu(v);
            h[nt] = v; sum += v; sumsq += v * v;
        }
#pragma unroll
        for (int m = 1; m < 16; m <<= 1) {
            sum += __shfl_xor(sum, m);
            sumsq += __shfl_xor(sumsq, m);
        }
        float mean = sum * (1.f / 128.f);
        float var = sumsq * (1.f / 128.f) - mean * mean;
        float rs = rsqrtf(var + 1e-5f);
#pragma unroll
        for (int nt = 0; nt < 8; ++nt) {
            int c = nt * 16 + ln;
            float a = (h[nt] - mean) * rs * g[nt] + bt[nt];
            tgt_out[(size_t)row * D + c] = tgt_feat[(size_t)row * D + c] + a;
        }
    }
}

extern "C" void kernel_launch(void* const* d_in, const int* in_sizes, int n_in,
                              void* d_out, int out_size, void* d_ws, size_t ws_size,
                              hipStream_t stream) {
    const float* src_feat  = (const float*)d_in[0];
    const float* tgt_feat  = (const float*)d_in[1];
    const float* edge_feat = (const float*)d_in[2];
    const float* Ws2e = (const float*)d_in[3];
    const float* We2e = (const float*)d_in[4];
    const float* We2t = (const float*)d_in[5];
    const float* Wt2t = (const float*)d_in[6];
    const float* gamma1 = (const float*)d_in[7];
    const float* beta1  = (const float*)d_in[8];
    const float* gamma2 = (const float*)d_in[9];
    const float* beta2  = (const float*)d_in[10];
    const int* src_idx = (const int*)d_in[11];
    const int* tgt_idx = (const int*)d_in[12];

    int n_src  = in_sizes[0] / D;
    int n_tgt  = in_sizes[1] / D;
    int n_edge = in_sizes[2] / D;

    float* edge_out = (float*)d_out;
    float* tgt_out  = (float*)d_out + (size_t)n_edge * D;

    // workspace layout
    char* ws = (char*)d_ws;
    unsigned short* Wb = (unsigned short*)ws;                     // 4 * 16384 bf16 = 128 KB
    float* Sp     = (float*)(ws + 4 * 16384 * 2);                 // [n_src, D]
    float* Tp     = Sp + (size_t)n_src * D;                       // [n_tgt, D]
    float* Ttp    = Tp + (size_t)n_tgt * D;                       // [n_tgt, D]
    float* sums   = Ttp + (size_t)n_tgt * D;                      // [n_tgt, D]
    float* counts = sums + (size_t)n_tgt * D;                     // [n_tgt]

    // zero sums + counts (contiguous)
    hipMemsetAsync(sums, 0, ((size_t)n_tgt * D + n_tgt) * sizeof(float), stream);

    convert_weights<<<256, 256, 0, stream>>>(Ws2e, We2e, We2t, Wt2t, Wb);
    count_edges<<<(n_edge + 255) / 256, 256, 0, stream>>>(tgt_idx, counts, n_edge);

    // node projections through Ws2e (and tgt through Wt2t)
    proj_kernel<<<(n_src + BM - 1) / BM, 256, 0, stream>>>(src_feat, Wb,             Sp,  n_src);
    proj_kernel<<<(n_tgt + BM - 1) / BM, 256, 0, stream>>>(tgt_feat, Wb,             Tp,  n_tgt);
    proj_kernel<<<(n_tgt + BM - 1) / BM, 256, 0, stream>>>(tgt_feat, Wb + 3 * 16384, Ttp, n_tgt);

    edge_kernel<<<(n_edge + BM - 1) / BM, 256, 0, stream>>>(
        edge_feat, Wb + 16384, Sp, Tp, src_idx, tgt_idx, gamma1, beta1,
        edge_out, sums, n_edge);

    node_kernel<<<(n_tgt + BM - 1) / BM, 256, 0, stream>>>(
        sums, counts, Wb + 2 * 16384, Ttp, tgt_feat, gamma2, beta2,
        tgt_out, n_tgt);
}